// Round 1
// baseline (333.682 us; speedup 1.0000x reference)
//
#include <hip/hip_runtime.h>

#define D_IN 128
#define D_OUT 64

__device__ __forceinline__ unsigned int ford(float f) {
    unsigned int u = __float_as_uint(f);
    return (u & 0x80000000u) ? ~u : (u | 0x80000000u);
}
__device__ __forceinline__ float funord(unsigned int u) {
    u = (u & 0x80000000u) ? (u & 0x7fffffffu) : ~u;
    return __uint_as_float(u);
}

// K0: tiny precompute of M[64][2] and c[2]
__global__ void precompute_kernel(const float* __restrict__ W_attn,
                                  const float* __restrict__ W_eatt,
                                  const float* __restrict__ W_e2n,
                                  const float* __restrict__ W_edge,
                                  const float* __restrict__ attn_edge,
                                  float* __restrict__ Mbuf,
                                  float* __restrict__ cbuf) {
    int d = threadIdx.x;  // 0..63
    // M[d][j] = sum_k W_e2n[d,k] * W_eatt[k,j]
    Mbuf[d * 2 + 0] = W_e2n[d * 2 + 0] * W_eatt[0] + W_e2n[d * 2 + 1] * W_eatt[2];
    Mbuf[d * 2 + 1] = W_e2n[d * 2 + 0] * W_eatt[1] + W_e2n[d * 2 + 1] * W_eatt[3];
    // w_ee[k] = sum_d W_edge[d,k] * attn_edge[d]  (wave reduce over 64 lanes)
    float p0 = W_edge[d * 2 + 0] * attn_edge[d];
    float p1 = W_edge[d * 2 + 1] * attn_edge[d];
    for (int off = 32; off; off >>= 1) {
        p0 += __shfl_xor(p0, off);
        p1 += __shfl_xor(p1, off);
    }
    if (d == 0) {
        float t0 = W_attn[128] + p0;
        float t1 = W_attn[129] + p1;
        // c[j] = sum_k W_eatt[k,j] * t[k]
        cbuf[0] = W_eatt[0] * t0 + W_eatt[2] * t1;
        cbuf[1] = W_eatt[1] * t0 + W_eatt[3] * t1;
    }
}

// K1: zero h_out, init m_ord to 0 (== below ford(-inf)), s to 0
__global__ void init_kernel(float* __restrict__ hout,
                            unsigned int* __restrict__ m_ord,
                            float* __restrict__ sbuf, int N) {
    int i = blockIdx.x * 256 + threadIdx.x;
    int stride = gridDim.x * 256;
    int total = N * D_OUT;
    for (int idx = i; idx < total; idx += stride) hout[idx] = 0.f;
    for (int idx = i; idx < N; idx += stride) {
        m_ord[idx] = 0u;
        sbuf[idx] = 0.f;
    }
}

// K2: z = h @ W_fc^T ; as[n] = z[n].W_attn[0:64] ; ad[n] = z[n].W_attn[64:128]
// one wave per node, 4 nodes per 256-thread block
__global__ __launch_bounds__(256) void node_kernel(const float* __restrict__ h,
                                                   const float* __restrict__ W_fc,
                                                   const float* __restrict__ W_attn,
                                                   float* __restrict__ z,
                                                   float* __restrict__ as_,
                                                   float* __restrict__ ad_, int N) {
    __shared__ float wfc[D_OUT * (D_IN + 1)];  // +1 pad: kill stride-128 bank conflict
    __shared__ float hrow[4][D_IN];
    for (int idx = threadIdx.x; idx < D_OUT * D_IN; idx += 256) {
        int r = idx >> 7, k = idx & 127;
        wfc[r * (D_IN + 1) + k] = W_fc[idx];
    }
    int n0 = blockIdx.x * 4;
    for (int idx = threadIdx.x; idx < 4 * D_IN; idx += 256) {
        int r = idx >> 7, k = idx & 127;
        int n = n0 + r;
        hrow[r][k] = (n < N) ? h[(size_t)n * D_IN + k] : 0.f;
    }
    __syncthreads();
    int w = threadIdx.x >> 6, l = threadIdx.x & 63;
    int n = n0 + w;
    if (n >= N) return;
    const float* hr = hrow[w];
    const float* wr = &wfc[l * (D_IN + 1)];
    float acc = 0.f;
#pragma unroll 8
    for (int k = 0; k < D_IN; ++k) acc = fmaf(hr[k], wr[k], acc);
    z[(size_t)n * D_OUT + l] = acc;
    float pa = acc * W_attn[l];
    float pb = acc * W_attn[64 + l];
    for (int off = 32; off; off >>= 1) {
        pa += __shfl_xor(pa, off);
        pb += __shfl_xor(pb, off);
    }
    if (l == 0) {
        as_[n] = pa;
        ad_[n] = pb;
    }
}

// K3: per-edge logit + segment max (ordered-int atomicMax)
__global__ void edge_logit_kernel(const float* __restrict__ e,
                                  const int* __restrict__ src,
                                  const int* __restrict__ dst,
                                  const float* __restrict__ as_,
                                  const float* __restrict__ ad_,
                                  const float* __restrict__ cbuf,
                                  float* __restrict__ logit,
                                  unsigned int* __restrict__ m_ord, int E) {
    int i = blockIdx.x * 256 + threadIdx.x;
    if (i >= E) return;
    int si = src[i], di = dst[i];
    float a = as_[si] + ad_[di] + e[i * 2] * cbuf[0] + e[i * 2 + 1] * cbuf[1];
    float lg = a > 0.f ? a : 0.01f * a;
    logit[i] = lg;
    atomicMax(&m_ord[di], ford(lg));
}

// K4: w = exp(logit - m[dst]); s[dst] += w
__global__ void edge_exp_kernel(const int* __restrict__ dst,
                                const float* __restrict__ logit,
                                const unsigned int* __restrict__ m_ord,
                                float* __restrict__ wbuf,
                                float* __restrict__ sbuf, int E) {
    int i = blockIdx.x * 256 + threadIdx.x;
    if (i >= E) return;
    int di = dst[i];
    float m = funord(m_ord[di]);
    float w = __expf(logit[i] - m);
    wbuf[i] = w;
    atomicAdd(&sbuf[di], w);
}

// K5: scatter messages; one wave (64 lanes) per edge, lane = output dim
__global__ __launch_bounds__(256) void scatter_kernel(const float* __restrict__ z,
                                                      const float* __restrict__ e,
                                                      const int* __restrict__ src,
                                                      const int* __restrict__ dst,
                                                      const float* __restrict__ wbuf,
                                                      const float* __restrict__ sbuf,
                                                      const float* __restrict__ Mbuf,
                                                      float* __restrict__ hout, int E) {
    int wv = threadIdx.x >> 6, l = threadIdx.x & 63;
    int i = blockIdx.x * 4 + wv;
    if (i >= E) return;
    int si = src[i], di = dst[i];
    float attn = wbuf[i] / sbuf[di];
    float e0 = e[i * 2], e1 = e[i * 2 + 1];
    float ez = e0 * Mbuf[l * 2] + e1 * Mbuf[l * 2 + 1];
    float msg = attn * (z[(size_t)si * D_OUT + l] + ez);
    atomicAdd(&hout[(size_t)di * D_OUT + l], msg);
}

extern "C" void kernel_launch(void* const* d_in, const int* in_sizes, int n_in,
                              void* d_out, int out_size, void* d_ws, size_t ws_size,
                              hipStream_t stream) {
    const float* h = (const float*)d_in[0];
    const float* e = (const float*)d_in[1];
    const int* src = (const int*)d_in[2];
    const int* dst = (const int*)d_in[3];
    const float* W_fc = (const float*)d_in[4];
    const float* W_attn = (const float*)d_in[5];
    const float* W_eatt = (const float*)d_in[6];
    const float* W_e2n = (const float*)d_in[7];
    const float* W_edge = (const float*)d_in[8];
    const float* attn_edge = (const float*)d_in[9];
    float* hout = (float*)d_out;

    const int N = in_sizes[0] / D_IN;
    const int E = in_sizes[2];

    // workspace layout (floats)
    float* z = (float*)d_ws;          // N*64
    float* as_ = z + (size_t)N * 64;  // N
    float* ad_ = as_ + N;             // N
    float* logit = ad_ + N;           // E
    float* wbuf = logit + E;          // E
    float* sbuf = wbuf + E;           // N
    float* Mbuf = sbuf + N;           // 128
    float* cbuf = Mbuf + 128;         // 2
    unsigned int* m_ord = (unsigned int*)(cbuf + 2);  // N

    precompute_kernel<<<1, 64, 0, stream>>>(W_attn, W_eatt, W_e2n, W_edge, attn_edge,
                                            Mbuf, cbuf);
    init_kernel<<<2048, 256, 0, stream>>>(hout, m_ord, sbuf, N);
    node_kernel<<<(N + 3) / 4, 256, 0, stream>>>(h, W_fc, W_attn, z, as_, ad_, N);
    edge_logit_kernel<<<(E + 255) / 256, 256, 0, stream>>>(e, src, dst, as_, ad_, cbuf,
                                                           logit, m_ord, E);
    edge_exp_kernel<<<(E + 255) / 256, 256, 0, stream>>>(dst, logit, m_ord, wbuf, sbuf, E);
    scatter_kernel<<<(E + 3) / 4, 256, 0, stream>>>(z, e, src, dst, wbuf, sbuf, Mbuf,
                                                    hout, E);
}

// Round 2
// 232.310 us; speedup vs baseline: 1.4364x; 1.4364x over previous
//
#include <hip/hip_runtime.h>

#define D_IN 128
#define D_OUT 64
#define SCAN_B 512

// ---------- K0: tiny precompute of M[64][2] and c[2] ----------
__global__ void precompute_kernel(const float* __restrict__ W_attn,
                                  const float* __restrict__ W_eatt,
                                  const float* __restrict__ W_e2n,
                                  const float* __restrict__ W_edge,
                                  const float* __restrict__ attn_edge,
                                  float* __restrict__ Mbuf,
                                  float* __restrict__ cbuf) {
    int d = threadIdx.x;  // 0..63
    Mbuf[d * 2 + 0] = W_e2n[d * 2 + 0] * W_eatt[0] + W_e2n[d * 2 + 1] * W_eatt[2];
    Mbuf[d * 2 + 1] = W_e2n[d * 2 + 0] * W_eatt[1] + W_e2n[d * 2 + 1] * W_eatt[3];
    float p0 = W_edge[d * 2 + 0] * attn_edge[d];
    float p1 = W_edge[d * 2 + 1] * attn_edge[d];
    for (int off = 32; off; off >>= 1) {
        p0 += __shfl_xor(p0, off);
        p1 += __shfl_xor(p1, off);
    }
    if (d == 0) {
        float t0 = W_attn[128] + p0;
        float t1 = W_attn[129] + p1;
        cbuf[0] = W_eatt[0] * t0 + W_eatt[2] * t1;
        cbuf[1] = W_eatt[1] * t0 + W_eatt[3] * t1;
    }
}

// ---------- zero int array ----------
__global__ void zero_int_kernel(int* __restrict__ p, int n) {
    int i = blockIdx.x * 256 + threadIdx.x;
    if (i < n) p[i] = 0;
}

// ---------- histogram of dst ----------
__global__ void hist_kernel(const int* __restrict__ dst, int* __restrict__ deg, int E) {
    int i = blockIdx.x * 256 + threadIdx.x;
    if (i < E) atomicAdd(&deg[dst[i]], 1);
}

// ---------- exclusive scan (3 passes) ----------
__global__ void scan1_kernel(const int* __restrict__ deg, int* __restrict__ excl,
                             int* __restrict__ bsum, int N) {
    __shared__ int tmp[SCAN_B];
    int i = blockIdx.x * SCAN_B + threadIdx.x;
    int v = (i < N) ? deg[i] : 0;
    tmp[threadIdx.x] = v;
    __syncthreads();
    for (int off = 1; off < SCAN_B; off <<= 1) {
        int t = (threadIdx.x >= (unsigned)off) ? tmp[threadIdx.x - off] : 0;
        __syncthreads();
        tmp[threadIdx.x] += t;
        __syncthreads();
    }
    if (i < N) excl[i] = tmp[threadIdx.x] - v;
    if (threadIdx.x == SCAN_B - 1) bsum[blockIdx.x] = tmp[threadIdx.x];
}

__global__ void scan2_kernel(int* __restrict__ bsum, int nb) {
    __shared__ int tmp[128];
    int v = (threadIdx.x < (unsigned)nb) ? bsum[threadIdx.x] : 0;
    tmp[threadIdx.x] = v;
    __syncthreads();
    for (int off = 1; off < 128; off <<= 1) {
        int t = (threadIdx.x >= (unsigned)off) ? tmp[threadIdx.x - off] : 0;
        __syncthreads();
        tmp[threadIdx.x] += t;
        __syncthreads();
    }
    if (threadIdx.x < (unsigned)nb) bsum[threadIdx.x] = tmp[threadIdx.x] - v;
}

__global__ void scan3_kernel(const int* __restrict__ excl, const int* __restrict__ bsum,
                             int* __restrict__ row_start, int* __restrict__ cursor,
                             int N, int E) {
    int i = blockIdx.x * SCAN_B + threadIdx.x;
    if (i < N) {
        int v = excl[i] + bsum[blockIdx.x];
        row_start[i] = v;
        cursor[i] = v;
    }
    if (i == 0) row_start[N] = E;
}

// ---------- build CSR edge list (grouped by dst) ----------
__global__ void build_kernel(const int* __restrict__ dst, int* __restrict__ cursor,
                             int* __restrict__ eid, int E) {
    int i = blockIdx.x * 256 + threadIdx.x;
    if (i >= E) return;
    int pos = atomicAdd(&cursor[dst[i]], 1);
    eid[pos] = i;
}

// ---------- node GEMM: z = h @ W_fc^T; as/ad per node ----------
__global__ __launch_bounds__(256) void node_kernel(const float* __restrict__ h,
                                                   const float* __restrict__ W_fc,
                                                   const float* __restrict__ W_attn,
                                                   float* __restrict__ z,
                                                   float* __restrict__ as_,
                                                   float* __restrict__ ad_, int N) {
    __shared__ float wfc[D_OUT * (D_IN + 1)];
    __shared__ float hrow[4][D_IN];
    for (int idx = threadIdx.x; idx < D_OUT * D_IN; idx += 256) {
        int r = idx >> 7, k = idx & 127;
        wfc[r * (D_IN + 1) + k] = W_fc[idx];
    }
    int n0 = blockIdx.x * 4;
    for (int idx = threadIdx.x; idx < 4 * D_IN; idx += 256) {
        int r = idx >> 7, k = idx & 127;
        int n = n0 + r;
        hrow[r][k] = (n < N) ? h[(size_t)n * D_IN + k] : 0.f;
    }
    __syncthreads();
    int w = threadIdx.x >> 6, l = threadIdx.x & 63;
    int n = n0 + w;
    if (n >= N) return;
    const float* hr = hrow[w];
    const float* wr = &wfc[l * (D_IN + 1)];
    float acc = 0.f;
#pragma unroll 8
    for (int k = 0; k < D_IN; ++k) acc = fmaf(hr[k], wr[k], acc);
    z[(size_t)n * D_OUT + l] = acc;
    float pa = acc * W_attn[l];
    float pb = acc * W_attn[64 + l];
    for (int off = 32; off; off >>= 1) {
        pa += __shfl_xor(pa, off);
        pb += __shfl_xor(pb, off);
    }
    if (l == 0) {
        as_[n] = pa;
        ad_[n] = pb;
    }
}

// ---------- fused per-node softmax + weighted aggregation ----------
// one wave per node, lane = output dim; no atomics anywhere
__global__ __launch_bounds__(256) void fused_kernel(const float* __restrict__ z,
                                                    const float* __restrict__ e,
                                                    const int* __restrict__ src,
                                                    const float* __restrict__ as_,
                                                    const float* __restrict__ ad_,
                                                    const int* __restrict__ row_start,
                                                    const int* __restrict__ eid,
                                                    const float* __restrict__ Mbuf,
                                                    const float* __restrict__ cbuf,
                                                    float* __restrict__ hout, int N) {
    int wv = threadIdx.x >> 6, l = threadIdx.x & 63;
    int n = blockIdx.x * 4 + wv;
    if (n >= N) return;
    int start = row_start[n], end = row_start[n + 1];
    float* outp = &hout[(size_t)n * D_OUT + l];
    if (start == end) {  // no incoming edges
        *outp = 0.f;
        return;
    }
    float c0 = cbuf[0], c1 = cbuf[1];
    float M0 = Mbuf[l * 2], M1 = Mbuf[l * 2 + 1];
    float adn = ad_[n];

    // phase A: segment max (exact, in-register)
    float mx = -INFINITY;
    for (int j = start + l; j < end; j += 64) {
        int i = eid[j];
        float2 ev = ((const float2*)e)[i];
        float lg = as_[src[i]] + adn + ev.x * c0 + ev.y * c1;
        lg = lg > 0.f ? lg : 0.01f * lg;
        mx = fmaxf(mx, lg);
    }
    for (int off = 32; off; off >>= 1) mx = fmaxf(mx, __shfl_xor(mx, off));

    // phase B: w = exp(lg - m); accumulate unnormalized messages + denom
    float acc = 0.f, s = 0.f;
    for (int base = start; base < end; base += 64) {
        int j = base + l;
        float w = 0.f, e0 = 0.f, e1 = 0.f;
        int sj = 0;
        if (j < end) {
            int i = eid[j];
            sj = src[i];
            float2 ev = ((const float2*)e)[i];
            e0 = ev.x;
            e1 = ev.y;
            float lg = as_[sj] + adn + e0 * c0 + e1 * c1;
            lg = lg > 0.f ? lg : 0.01f * lg;
            w = __expf(lg - mx);
        }
        s += w;
        int cnt = end - base;
        if (cnt > 64) cnt = 64;
        for (int jj = 0; jj < cnt; ++jj) {
            float wj = __shfl(w, jj);
            float a0 = __shfl(e0, jj);
            float a1 = __shfl(e1, jj);
            int sjj = __shfl(sj, jj);
            acc = fmaf(wj, z[(size_t)sjj * D_OUT + l] + fmaf(a0, M0, a1 * M1), acc);
        }
    }
    for (int off = 32; off; off >>= 1) s += __shfl_xor(s, off);
    *outp = acc / s;
}

extern "C" void kernel_launch(void* const* d_in, const int* in_sizes, int n_in,
                              void* d_out, int out_size, void* d_ws, size_t ws_size,
                              hipStream_t stream) {
    const float* h = (const float*)d_in[0];
    const float* e = (const float*)d_in[1];
    const int* src = (const int*)d_in[2];
    const int* dst = (const int*)d_in[3];
    const float* W_fc = (const float*)d_in[4];
    const float* W_attn = (const float*)d_in[5];
    const float* W_eatt = (const float*)d_in[6];
    const float* W_e2n = (const float*)d_in[7];
    const float* W_edge = (const float*)d_in[8];
    const float* attn_edge = (const float*)d_in[9];
    float* hout = (float*)d_out;

    const int N = in_sizes[0] / D_IN;
    const int E = in_sizes[2];
    const int nb = (N + SCAN_B - 1) / SCAN_B;

    // workspace layout
    float* z = (float*)d_ws;            // N*64 f32
    float* as_ = z + (size_t)N * 64;    // N
    float* ad_ = as_ + N;               // N
    float* Mbuf = ad_ + N;              // 128
    float* cbuf = Mbuf + 128;           // 2
    int* deg = (int*)(cbuf + 2);        // N
    int* excl = deg + N;                // N
    int* bsum = excl + N;               // nb (<=128)
    int* row_start = bsum + 128;        // N+1
    int* cursor = row_start + N + 1;    // N
    int* eid = cursor + N;              // E

    precompute_kernel<<<1, 64, 0, stream>>>(W_attn, W_eatt, W_e2n, W_edge, attn_edge,
                                            Mbuf, cbuf);
    zero_int_kernel<<<(N + 255) / 256, 256, 0, stream>>>(deg, N);
    hist_kernel<<<(E + 255) / 256, 256, 0, stream>>>(dst, deg, E);
    scan1_kernel<<<nb, SCAN_B, 0, stream>>>(deg, excl, bsum, N);
    scan2_kernel<<<1, 128, 0, stream>>>(bsum, nb);
    scan3_kernel<<<nb, SCAN_B, 0, stream>>>(excl, bsum, row_start, cursor, N, E);
    build_kernel<<<(E + 255) / 256, 256, 0, stream>>>(dst, cursor, eid, E);
    node_kernel<<<(N + 3) / 4, 256, 0, stream>>>(h, W_fc, W_attn, z, as_, ad_, N);
    fused_kernel<<<(N + 3) / 4, 256, 0, stream>>>(z, e, src, as_, ad_, row_start, eid,
                                                  Mbuf, cbuf, hout, N);
}

// Round 3
// 189.928 us; speedup vs baseline: 1.7569x; 1.2231x over previous
//
#include <hip/hip_runtime.h>

#define D_IN 128
#define D_OUT 64
#define SCAN_B 512

// ---------- K0: tiny precompute of M[64][2] and c[2] ----------
__global__ void precompute_kernel(const float* __restrict__ W_attn,
                                  const float* __restrict__ W_eatt,
                                  const float* __restrict__ W_e2n,
                                  const float* __restrict__ W_edge,
                                  const float* __restrict__ attn_edge,
                                  float* __restrict__ Mbuf,
                                  float* __restrict__ cbuf) {
    int d = threadIdx.x;  // 0..63
    Mbuf[d * 2 + 0] = W_e2n[d * 2 + 0] * W_eatt[0] + W_e2n[d * 2 + 1] * W_eatt[2];
    Mbuf[d * 2 + 1] = W_e2n[d * 2 + 0] * W_eatt[1] + W_e2n[d * 2 + 1] * W_eatt[3];
    float p0 = W_edge[d * 2 + 0] * attn_edge[d];
    float p1 = W_edge[d * 2 + 1] * attn_edge[d];
    for (int off = 32; off; off >>= 1) {
        p0 += __shfl_xor(p0, off);
        p1 += __shfl_xor(p1, off);
    }
    if (d == 0) {
        float t0 = W_attn[128] + p0;
        float t1 = W_attn[129] + p1;
        cbuf[0] = W_eatt[0] * t0 + W_eatt[2] * t1;
        cbuf[1] = W_eatt[1] * t0 + W_eatt[3] * t1;
    }
}

// ---------- histogram of dst ----------
__global__ void hist_kernel(const int* __restrict__ dst, int* __restrict__ deg, int E) {
    int i = blockIdx.x * 256 + threadIdx.x;
    if (i < E) atomicAdd(&deg[dst[i]], 1);
}

// ---------- exclusive scan (3 passes) ----------
__global__ void scan1_kernel(const int* __restrict__ deg, int* __restrict__ excl,
                             int* __restrict__ bsum, int N) {
    __shared__ int tmp[SCAN_B];
    int i = blockIdx.x * SCAN_B + threadIdx.x;
    int v = (i < N) ? deg[i] : 0;
    tmp[threadIdx.x] = v;
    __syncthreads();
    for (int off = 1; off < SCAN_B; off <<= 1) {
        int t = (threadIdx.x >= (unsigned)off) ? tmp[threadIdx.x - off] : 0;
        __syncthreads();
        tmp[threadIdx.x] += t;
        __syncthreads();
    }
    if (i < N) excl[i] = tmp[threadIdx.x] - v;
    if (threadIdx.x == SCAN_B - 1) bsum[blockIdx.x] = tmp[threadIdx.x];
}

__global__ void scan2_kernel(int* __restrict__ bsum, int nb) {
    __shared__ int tmp[128];
    int v = (threadIdx.x < (unsigned)nb) ? bsum[threadIdx.x] : 0;
    tmp[threadIdx.x] = v;
    __syncthreads();
    for (int off = 1; off < 128; off <<= 1) {
        int t = (threadIdx.x >= (unsigned)off) ? tmp[threadIdx.x - off] : 0;
        __syncthreads();
        tmp[threadIdx.x] += t;
        __syncthreads();
    }
    if (threadIdx.x < (unsigned)nb) bsum[threadIdx.x] = tmp[threadIdx.x] - v;
}

__global__ void scan3_kernel(const int* __restrict__ excl, const int* __restrict__ bsum,
                             int* __restrict__ row_start, int* __restrict__ cursor,
                             int N, int E) {
    int i = blockIdx.x * SCAN_B + threadIdx.x;
    if (i < N) {
        int v = excl[i] + bsum[blockIdx.x];
        row_start[i] = v;
        cursor[i] = v;
    }
    if (i == 0) row_start[N] = E;
}

// ---------- node GEMM: z = h @ W_fc^T, 64x64x128 block, 4x4 microtile ----------
// epilogue folds as_[n] = z[n].W_attn[0:64], ad_[n] = z[n].W_attn[64:128]
__global__ __launch_bounds__(256) void node_gemm_kernel(const float* __restrict__ h,
                                                        const float* __restrict__ W_fc,
                                                        const float* __restrict__ W_attn,
                                                        float* __restrict__ z,
                                                        float* __restrict__ as_,
                                                        float* __restrict__ ad_, int N) {
    __shared__ float As[64][132];  // pad 128->132 to break bank alignment
    __shared__ float Bs[64][132];
    int t = threadIdx.x;
    int n0 = blockIdx.x * 64;
    for (int idx = t; idx < 64 * 32; idx += 256) {
        int r = idx >> 5, c4 = idx & 31;
        float4 v = make_float4(0.f, 0.f, 0.f, 0.f);
        if (n0 + r < N) v = ((const float4*)h)[(size_t)(n0 + r) * 32 + c4];
        *(float4*)&As[r][c4 * 4] = v;
    }
    for (int idx = t; idx < 64 * 32; idx += 256) {
        int r = idx >> 5, c4 = idx & 31;
        float4 v = ((const float4*)W_fc)[r * 32 + c4];
        *(float4*)&Bs[r][c4 * 4] = v;
    }
    __syncthreads();
    int tx = t & 15, ty = t >> 4;  // tx -> dim group, ty -> node group
    float acc[4][4] = {};
    for (int k = 0; k < D_IN; k += 4) {
        float4 a[4], b[4];
#pragma unroll
        for (int i = 0; i < 4; ++i) a[i] = *(const float4*)&As[ty * 4 + i][k];
#pragma unroll
        for (int j = 0; j < 4; ++j) b[j] = *(const float4*)&Bs[tx * 4 + j][k];
#pragma unroll
        for (int i = 0; i < 4; ++i)
#pragma unroll
            for (int j = 0; j < 4; ++j) {
                acc[i][j] = fmaf(a[i].x, b[j].x, acc[i][j]);
                acc[i][j] = fmaf(a[i].y, b[j].y, acc[i][j]);
                acc[i][j] = fmaf(a[i].z, b[j].z, acc[i][j]);
                acc[i][j] = fmaf(a[i].w, b[j].w, acc[i][j]);
            }
    }
    float wa[4], wb[4];
#pragma unroll
    for (int j = 0; j < 4; ++j) {
        wa[j] = W_attn[tx * 4 + j];
        wb[j] = W_attn[64 + tx * 4 + j];
    }
#pragma unroll
    for (int i = 0; i < 4; ++i) {
        int n = n0 + ty * 4 + i;
        if (n >= N) break;
        float4 zv = make_float4(acc[i][0], acc[i][1], acc[i][2], acc[i][3]);
        ((float4*)z)[(size_t)n * 16 + tx] = zv;
        float pa = acc[i][0] * wa[0] + acc[i][1] * wa[1] + acc[i][2] * wa[2] + acc[i][3] * wa[3];
        float pb = acc[i][0] * wb[0] + acc[i][1] * wb[1] + acc[i][2] * wb[2] + acc[i][3] * wb[3];
        for (int off = 8; off; off >>= 1) {
            pa += __shfl_xor(pa, off);
            pb += __shfl_xor(pb, off);
        }
        if (tx == 0) {
            as_[n] = pa;
            ad_[n] = pb;
        }
    }
}

// ---------- build CSR payload with precomputed logit ----------
// payload[pos] = {logit, src_bits, e0, e1}
__global__ void build_logit_kernel(const float* __restrict__ e,
                                   const int* __restrict__ src,
                                   const int* __restrict__ dst,
                                   const float* __restrict__ as_,
                                   const float* __restrict__ ad_,
                                   const float* __restrict__ cbuf,
                                   int* __restrict__ cursor,
                                   float4* __restrict__ pay, int E) {
    int i = blockIdx.x * 256 + threadIdx.x;
    if (i >= E) return;
    int si = src[i], di = dst[i];
    float2 ev = ((const float2*)e)[i];
    float a = as_[si] + ad_[di] + ev.x * cbuf[0] + ev.y * cbuf[1];
    float lg = a > 0.f ? a : 0.01f * a;
    int pos = atomicAdd(&cursor[di], 1);
    pay[pos] = make_float4(lg, __int_as_float(si), ev.x, ev.y);
}

// ---------- fused per-node softmax + aggregation; coalesced payload ----------
__global__ __launch_bounds__(256) void fused_kernel(const float* __restrict__ z,
                                                    const float4* __restrict__ pay,
                                                    const int* __restrict__ row_start,
                                                    const float* __restrict__ Mbuf,
                                                    float* __restrict__ hout, int N) {
    int wv = threadIdx.x >> 6, l = threadIdx.x & 63;
    int n = blockIdx.x * 4 + wv;
    if (n >= N) return;
    int start = row_start[n], end = row_start[n + 1];
    int deg = end - start;
    if (deg == 0) {
        hout[(size_t)n * D_OUT + l] = 0.f;
        return;
    }
    float M0 = Mbuf[l * 2], M1 = Mbuf[l * 2 + 1];
    bool single = (deg <= 64);
    float4 P0 = make_float4(-INFINITY, 0.f, 0.f, 0.f);
    float mx = -INFINITY;
    if (single) {
        if (l < deg) P0 = pay[start + l];
        mx = P0.x;
    } else {
        for (int j = start + l; j < end; j += 64) mx = fmaxf(mx, pay[j].x);
    }
    for (int off = 32; off; off >>= 1) mx = fmaxf(mx, __shfl_xor(mx, off));
    float sl = 0.f, s0l = 0.f, s1l = 0.f, accz = 0.f;
    for (int base = start; base < end; base += 64) {
        int j = base + l;
        float4 P = P0;
        if (!single && j < end) P = pay[j];
        float w = (j < end) ? __expf(P.x - mx) : 0.f;
        sl += w;
        s0l = fmaf(w, P.z, s0l);
        s1l = fmaf(w, P.w, s1l);
        int sj = __float_as_int(P.y);
        int cnt = end - base;
        if (cnt > 64) cnt = 64;
        for (int jj = 0; jj < cnt; ++jj) {
            float wb = __shfl(w, jj);
            int sb = __shfl(sj, jj);
            accz = fmaf(wb, z[(size_t)sb * D_OUT + l], accz);
        }
    }
    for (int off = 32; off; off >>= 1) {
        sl += __shfl_xor(sl, off);
        s0l += __shfl_xor(s0l, off);
        s1l += __shfl_xor(s1l, off);
    }
    hout[(size_t)n * D_OUT + l] = (accz + fmaf(M0, s0l, M1 * s1l)) / sl;
}

extern "C" void kernel_launch(void* const* d_in, const int* in_sizes, int n_in,
                              void* d_out, int out_size, void* d_ws, size_t ws_size,
                              hipStream_t stream) {
    const float* h = (const float*)d_in[0];
    const float* e = (const float*)d_in[1];
    const int* src = (const int*)d_in[2];
    const int* dst = (const int*)d_in[3];
    const float* W_fc = (const float*)d_in[4];
    const float* W_attn = (const float*)d_in[5];
    const float* W_eatt = (const float*)d_in[6];
    const float* W_e2n = (const float*)d_in[7];
    const float* W_edge = (const float*)d_in[8];
    const float* attn_edge = (const float*)d_in[9];
    float* hout = (float*)d_out;

    const int N = in_sizes[0] / D_IN;
    const int E = in_sizes[2];
    const int nb = (N + SCAN_B - 1) / SCAN_B;

    // workspace layout (16B-aligned payload first)
    float4* pay = (float4*)d_ws;              // E float4
    float* z = (float*)(pay + E);             // N*64
    float* as_ = z + (size_t)N * 64;          // N
    float* ad_ = as_ + N;                     // N
    float* Mbuf = ad_ + N;                    // 128
    float* cbuf = Mbuf + 128;                 // 2
    int* deg = (int*)(cbuf + 2);              // N
    int* excl = deg + N;                      // N
    int* bsum = excl + N;                     // <=128
    int* row_start = bsum + 128;              // N+1
    int* cursor = row_start + N + 1;          // N

    precompute_kernel<<<1, 64, 0, stream>>>(W_attn, W_eatt, W_e2n, W_edge, attn_edge,
                                            Mbuf, cbuf);
    hipMemsetAsync(deg, 0, (size_t)N * sizeof(int), stream);
    hist_kernel<<<(E + 255) / 256, 256, 0, stream>>>(dst, deg, E);
    scan1_kernel<<<nb, SCAN_B, 0, stream>>>(deg, excl, bsum, N);
    scan2_kernel<<<1, 128, 0, stream>>>(bsum, nb);
    scan3_kernel<<<nb, SCAN_B, 0, stream>>>(excl, bsum, row_start, cursor, N, E);
    node_gemm_kernel<<<(N + 63) / 64, 256, 0, stream>>>(h, W_fc, W_attn, z, as_, ad_, N);
    build_logit_kernel<<<(E + 255) / 256, 256, 0, stream>>>(e, src, dst, as_, ad_, cbuf,
                                                            cursor, pay, E);
    fused_kernel<<<(N + 3) / 4, 256, 0, stream>>>(z, pay, row_start, Mbuf, hout, N);
}

// Round 4
// 163.367 us; speedup vs baseline: 2.0425x; 1.1626x over previous
//
#include <hip/hip_runtime.h>

#define D_IN 128
#define D_OUT 64
#define SCAN_B 512

// ---------- K0: tiny precompute of M0[64], M1[64] and c[2] ----------
__global__ void precompute_kernel(const float* __restrict__ W_attn,
                                  const float* __restrict__ W_eatt,
                                  const float* __restrict__ W_e2n,
                                  const float* __restrict__ W_edge,
                                  const float* __restrict__ attn_edge,
                                  float* __restrict__ M0buf,
                                  float* __restrict__ M1buf,
                                  float* __restrict__ cbuf) {
    int d = threadIdx.x;  // 0..63
    M0buf[d] = W_e2n[d * 2 + 0] * W_eatt[0] + W_e2n[d * 2 + 1] * W_eatt[2];
    M1buf[d] = W_e2n[d * 2 + 0] * W_eatt[1] + W_e2n[d * 2 + 1] * W_eatt[3];
    float p0 = W_edge[d * 2 + 0] * attn_edge[d];
    float p1 = W_edge[d * 2 + 1] * attn_edge[d];
    for (int off = 32; off; off >>= 1) {
        p0 += __shfl_xor(p0, off);
        p1 += __shfl_xor(p1, off);
    }
    if (d == 0) {
        float t0 = W_attn[128] + p0;
        float t1 = W_attn[129] + p1;
        cbuf[0] = W_eatt[0] * t0 + W_eatt[2] * t1;
        cbuf[1] = W_eatt[1] * t0 + W_eatt[3] * t1;
    }
}

// ---------- histogram of dst ----------
__global__ void hist_kernel(const int* __restrict__ dst, int* __restrict__ deg, int E) {
    int i = blockIdx.x * 256 + threadIdx.x;
    if (i < E) atomicAdd(&deg[dst[i]], 1);
}

// ---------- exclusive scan (3 passes) ----------
__global__ void scan1_kernel(const int* __restrict__ deg, int* __restrict__ excl,
                             int* __restrict__ bsum, int N) {
    __shared__ int wsum[8];
    int i = blockIdx.x * SCAN_B + threadIdx.x;
    int v = (i < N) ? deg[i] : 0;
    int lane = threadIdx.x & 63, w = threadIdx.x >> 6;
    int sc = v;
    for (int off = 1; off < 64; off <<= 1) {
        int t = __shfl_up(sc, off);
        if (lane >= off) sc += t;
    }
    if (lane == 63) wsum[w] = sc;
    __syncthreads();
    if (w == 0 && lane < 8) {
        int x = wsum[lane];
        for (int off = 1; off < 8; off <<= 1) {
            int t = __shfl_up(x, off);
            if (lane >= off) x += t;
        }
        wsum[lane] = x;
    }
    __syncthreads();
    int wofs = (w > 0) ? wsum[w - 1] : 0;
    if (i < N) excl[i] = wofs + sc - v;
    if (threadIdx.x == SCAN_B - 1) bsum[blockIdx.x] = wofs + sc;
}

__global__ void scan2_kernel(int* __restrict__ bsum, int nb) {
    __shared__ int tmp[128];
    int v = (threadIdx.x < (unsigned)nb) ? bsum[threadIdx.x] : 0;
    tmp[threadIdx.x] = v;
    __syncthreads();
    for (int off = 1; off < 128; off <<= 1) {
        int t = (threadIdx.x >= (unsigned)off) ? tmp[threadIdx.x - off] : 0;
        __syncthreads();
        tmp[threadIdx.x] += t;
        __syncthreads();
    }
    if (threadIdx.x < (unsigned)nb) bsum[threadIdx.x] = tmp[threadIdx.x] - v;
}

__global__ void scan3_kernel(const int* __restrict__ excl, const int* __restrict__ bsum,
                             int* __restrict__ row_start, int* __restrict__ cursor,
                             int N, int E) {
    int i = blockIdx.x * SCAN_B + threadIdx.x;
    if (i < N) {
        int v = excl[i] + bsum[blockIdx.x];
        row_start[i] = v;
        cursor[i] = v;
    }
    if (i == 0) row_start[N] = E;
}

// ---------- node GEMM: z = h @ W_fc^T, 64x64x128 block, 4x4 microtile ----------
__global__ __launch_bounds__(256) void node_gemm_kernel(const float* __restrict__ h,
                                                        const float* __restrict__ W_fc,
                                                        const float* __restrict__ W_attn,
                                                        float* __restrict__ z,
                                                        float* __restrict__ as_,
                                                        float* __restrict__ ad_, int N) {
    __shared__ float As[64][132];
    __shared__ float Bs[64][132];
    int t = threadIdx.x;
    int n0 = blockIdx.x * 64;
    for (int idx = t; idx < 64 * 32; idx += 256) {
        int r = idx >> 5, c4 = idx & 31;
        float4 v = make_float4(0.f, 0.f, 0.f, 0.f);
        if (n0 + r < N) v = ((const float4*)h)[(size_t)(n0 + r) * 32 + c4];
        *(float4*)&As[r][c4 * 4] = v;
    }
    for (int idx = t; idx < 64 * 32; idx += 256) {
        int r = idx >> 5, c4 = idx & 31;
        float4 v = ((const float4*)W_fc)[r * 32 + c4];
        *(float4*)&Bs[r][c4 * 4] = v;
    }
    __syncthreads();
    int tx = t & 15, ty = t >> 4;
    float acc[4][4] = {};
    for (int k = 0; k < D_IN; k += 4) {
        float4 a[4], b[4];
#pragma unroll
        for (int i = 0; i < 4; ++i) a[i] = *(const float4*)&As[ty * 4 + i][k];
#pragma unroll
        for (int j = 0; j < 4; ++j) b[j] = *(const float4*)&Bs[tx * 4 + j][k];
#pragma unroll
        for (int i = 0; i < 4; ++i)
#pragma unroll
            for (int j = 0; j < 4; ++j) {
                acc[i][j] = fmaf(a[i].x, b[j].x, acc[i][j]);
                acc[i][j] = fmaf(a[i].y, b[j].y, acc[i][j]);
                acc[i][j] = fmaf(a[i].z, b[j].z, acc[i][j]);
                acc[i][j] = fmaf(a[i].w, b[j].w, acc[i][j]);
            }
    }
    float wa[4], wb[4];
#pragma unroll
    for (int j = 0; j < 4; ++j) {
        wa[j] = W_attn[tx * 4 + j];
        wb[j] = W_attn[64 + tx * 4 + j];
    }
#pragma unroll
    for (int i = 0; i < 4; ++i) {
        int n = n0 + ty * 4 + i;
        if (n >= N) break;
        float4 zv = make_float4(acc[i][0], acc[i][1], acc[i][2], acc[i][3]);
        ((float4*)z)[(size_t)n * 16 + tx] = zv;
        float pa = acc[i][0] * wa[0] + acc[i][1] * wa[1] + acc[i][2] * wa[2] + acc[i][3] * wa[3];
        float pb = acc[i][0] * wb[0] + acc[i][1] * wb[1] + acc[i][2] * wb[2] + acc[i][3] * wb[3];
        for (int off = 8; off; off >>= 1) {
            pa += __shfl_xor(pa, off);
            pb += __shfl_xor(pb, off);
        }
        if (tx == 0) {
            as_[n] = pa;
            ad_[n] = pb;
        }
    }
}

// ---------- build CSR payload: {w=exp(logit), src_bits, e0, e1} ----------
// no max subtraction: logits are O(10) << 88, softmax is shift-invariant
__global__ void build_logit_kernel(const float* __restrict__ e,
                                   const int* __restrict__ src,
                                   const int* __restrict__ dst,
                                   const float* __restrict__ as_,
                                   const float* __restrict__ ad_,
                                   const float* __restrict__ cbuf,
                                   int* __restrict__ cursor,
                                   float4* __restrict__ pay, int E) {
    int i = blockIdx.x * 256 + threadIdx.x;
    if (i >= E) return;
    int si = src[i], di = dst[i];
    float2 ev = ((const float2*)e)[i];
    float a = as_[si] + ad_[di] + ev.x * cbuf[0] + ev.y * cbuf[1];
    float lg = a > 0.f ? a : 0.01f * a;
    float w = __expf(lg);
    int pos = atomicAdd(&cursor[di], 1);
    pay[pos] = make_float4(w, __int_as_float(si), ev.x, ev.y);
}

// ---------- fused aggregation: 4 edges/iter, float4 z-gather ----------
// lane = (g = edge subgroup 0..3, q = dim quad 0..15)
__global__ __launch_bounds__(256) void fused_kernel(const float* __restrict__ z,
                                                    const float4* __restrict__ pay,
                                                    const int* __restrict__ row_start,
                                                    const float* __restrict__ M0buf,
                                                    const float* __restrict__ M1buf,
                                                    float* __restrict__ hout, int N) {
    int wv = threadIdx.x >> 6, l = threadIdx.x & 63;
    int n = blockIdx.x * 4 + wv;
    if (n >= N) return;
    int start = row_start[n], end = row_start[n + 1];
    int g = l >> 4, q = l & 15;
    float4 acc = make_float4(0.f, 0.f, 0.f, 0.f);
    float s = 0.f, s0 = 0.f, s1 = 0.f;
    for (int base = start; base < end; base += 64) {
        int j = base + l;
        float w = 0.f, e0 = 0.f, e1 = 0.f;
        int sj = 0;
        if (j < end) {
            float4 P = pay[j];
            w = P.x;
            sj = __float_as_int(P.y);
            e0 = P.z;
            e1 = P.w;
        }
        s += w;
        s0 = fmaf(w, e0, s0);
        s1 = fmaf(w, e1, s1);
        int cnt = end - base;
        if (cnt > 64) cnt = 64;
        int iters = (cnt + 3) >> 2;
        for (int jj = 0; jj < iters; ++jj) {
            int srcl = jj * 4 + g;
            float wb = __shfl(w, srcl);     // lanes past cnt carry w=0, sj=0
            int sb = __shfl(sj, srcl);
            float4 zv = *(const float4*)&z[(size_t)sb * D_OUT + q * 4];
            acc.x = fmaf(wb, zv.x, acc.x);
            acc.y = fmaf(wb, zv.y, acc.y);
            acc.z = fmaf(wb, zv.z, acc.z);
            acc.w = fmaf(wb, zv.w, acc.w);
        }
    }
    // sum acc across the 4 edge subgroups
#pragma unroll
    for (int off = 16; off <= 32; off <<= 1) {
        acc.x += __shfl_xor(acc.x, off);
        acc.y += __shfl_xor(acc.y, off);
        acc.z += __shfl_xor(acc.z, off);
        acc.w += __shfl_xor(acc.w, off);
    }
    // wave-reduce s, s0, s1
    for (int off = 32; off; off >>= 1) {
        s += __shfl_xor(s, off);
        s0 += __shfl_xor(s0, off);
        s1 += __shfl_xor(s1, off);
    }
    if (g == 0) {
        float4 out = make_float4(0.f, 0.f, 0.f, 0.f);
        if (end > start) {
            float4 m0 = *(const float4*)&M0buf[q * 4];
            float4 m1 = *(const float4*)&M1buf[q * 4];
            float inv = 1.f / s;
            out.x = (acc.x + m0.x * s0 + m1.x * s1) * inv;
            out.y = (acc.y + m0.y * s0 + m1.y * s1) * inv;
            out.z = (acc.z + m0.z * s0 + m1.z * s1) * inv;
            out.w = (acc.w + m0.w * s0 + m1.w * s1) * inv;
        }
        *(float4*)&hout[(size_t)n * D_OUT + q * 4] = out;
    }
}

extern "C" void kernel_launch(void* const* d_in, const int* in_sizes, int n_in,
                              void* d_out, int out_size, void* d_ws, size_t ws_size,
                              hipStream_t stream) {
    const float* h = (const float*)d_in[0];
    const float* e = (const float*)d_in[1];
    const int* src = (const int*)d_in[2];
    const int* dst = (const int*)d_in[3];
    const float* W_fc = (const float*)d_in[4];
    const float* W_attn = (const float*)d_in[5];
    const float* W_eatt = (const float*)d_in[6];
    const float* W_e2n = (const float*)d_in[7];
    const float* W_edge = (const float*)d_in[8];
    const float* attn_edge = (const float*)d_in[9];
    float* hout = (float*)d_out;

    const int N = in_sizes[0] / D_IN;
    const int E = in_sizes[2];
    const int nb = (N + SCAN_B - 1) / SCAN_B;

    // workspace layout (16B-aligned payload first)
    float4* pay = (float4*)d_ws;              // E float4
    float* z = (float*)(pay + E);             // N*64
    float* as_ = z + (size_t)N * 64;          // N
    float* ad_ = as_ + N;                     // N
    float* M0buf = ad_ + N;                   // 64
    float* M1buf = M0buf + 64;                // 64
    float* cbuf = M1buf + 64;                 // 2
    int* deg = (int*)(cbuf + 2);              // N
    int* excl = deg + N;                      // N
    int* bsum = excl + N;                     // <=128
    int* row_start = bsum + 128;              // N+1
    int* cursor = row_start + N + 1;          // N

    precompute_kernel<<<1, 64, 0, stream>>>(W_attn, W_eatt, W_e2n, W_edge, attn_edge,
                                            M0buf, M1buf, cbuf);
    hipMemsetAsync(deg, 0, (size_t)N * sizeof(int), stream);
    hist_kernel<<<(E + 255) / 256, 256, 0, stream>>>(dst, deg, E);
    scan1_kernel<<<nb, SCAN_B, 0, stream>>>(deg, excl, bsum, N);
    scan2_kernel<<<1, 128, 0, stream>>>(bsum, nb);
    scan3_kernel<<<nb, SCAN_B, 0, stream>>>(excl, bsum, row_start, cursor, N, E);
    node_gemm_kernel<<<(N + 63) / 64, 256, 0, stream>>>(h, W_fc, W_attn, z, as_, ad_, N);
    build_logit_kernel<<<(E + 255) / 256, 256, 0, stream>>>(e, src, dst, as_, ad_, cbuf,
                                                            cursor, pay, E);
    fused_kernel<<<(N + 3) / 4, 256, 0, stream>>>(z, pay, row_start, M0buf, M1buf, hout, N);
}